// Round 1
// baseline (3020.051 us; speedup 1.0000x reference)
//
#include <hip/hip_runtime.h>
#include <hip/hip_bf16.h>

#define TS 64
#define KC 64

__global__ __launch_bounds__(256) void init_deg_k(float* deg, int N) {
    int i = blockIdx.x * 256 + threadIdx.x;
    if (i < N) deg[i] = 1.0f;  // self loop contributes 1
}

__global__ __launch_bounds__(256) void count_deg_k(const int* __restrict__ rows, float* deg, int E) {
    int e = blockIdx.x * 256 + threadIdx.x;
    if (e < E) atomicAdd(&deg[rows[e]], 1.0f);
}

__global__ __launch_bounds__(256) void dinv_k(float* deg, int N) {
    int i = blockIdx.x * 256 + threadIdx.x;
    if (i < N) deg[i] = rsqrtf(deg[i]);  // deg >= 1 guaranteed
}

// C[N,M] = A[N,K] @ W[K,M] + bias, fp32, 64x64 tile, 4x4 per thread
__global__ __launch_bounds__(256) void gemm_bias_k(
    const float* __restrict__ A, const float* __restrict__ W,
    const float* __restrict__ bias, float* __restrict__ C,
    int N, int K, int M)
{
    __shared__ float As[TS][KC + 4];
    __shared__ float Ws[KC][TS + 4];
    const int tid = threadIdx.x;
    const int tx = tid & 15;
    const int ty = tid >> 4;
    const int rowBase = blockIdx.x * TS;
    const int colBase = blockIdx.y * TS;

    float acc[4][4] = {};

    for (int k0 = 0; k0 < K; k0 += KC) {
        #pragma unroll
        for (int it = 0; it < 4; ++it) {
            int v = tid + 256 * it;     // float4 slot 0..1023
            int r = v >> 4;
            int kq = v & 15;
            int grow = rowBase + r;
            float4 val = make_float4(0.f, 0.f, 0.f, 0.f);
            if (grow < N) val = *(const float4*)(A + (size_t)grow * K + k0 + 4 * kq);
            *(float4*)(&As[r][4 * kq]) = val;
        }
        #pragma unroll
        for (int it = 0; it < 4; ++it) {
            int v = tid + 256 * it;
            int kk = v >> 4;
            int cq = v & 15;
            float4 val = *(const float4*)(W + (size_t)(k0 + kk) * M + colBase + 4 * cq);
            *(float4*)(&Ws[kk][4 * cq]) = val;
        }
        __syncthreads();

        #pragma unroll
        for (int k = 0; k < KC; ++k) {
            float a0 = As[ty * 4 + 0][k];
            float a1 = As[ty * 4 + 1][k];
            float a2 = As[ty * 4 + 2][k];
            float a3 = As[ty * 4 + 3][k];
            float b0 = Ws[k][tx * 4 + 0];
            float b1 = Ws[k][tx * 4 + 1];
            float b2 = Ws[k][tx * 4 + 2];
            float b3 = Ws[k][tx * 4 + 3];
            acc[0][0] += a0 * b0; acc[0][1] += a0 * b1; acc[0][2] += a0 * b2; acc[0][3] += a0 * b3;
            acc[1][0] += a1 * b0; acc[1][1] += a1 * b1; acc[1][2] += a1 * b2; acc[1][3] += a1 * b3;
            acc[2][0] += a2 * b0; acc[2][1] += a2 * b1; acc[2][2] += a2 * b2; acc[2][3] += a2 * b3;
            acc[3][0] += a3 * b0; acc[3][1] += a3 * b1; acc[3][2] += a3 * b2; acc[3][3] += a3 * b3;
        }
        __syncthreads();
    }

    const int gcol = colBase + tx * 4;
    float4 bv = *(const float4*)(bias + gcol);
    #pragma unroll
    for (int i = 0; i < 4; ++i) {
        int grow = rowBase + ty * 4 + i;
        if (grow >= N) continue;
        float4 out;
        out.x = acc[i][0] + bv.x;
        out.y = acc[i][1] + bv.y;
        out.z = acc[i][2] + bv.z;
        out.w = acc[i][3] + bv.w;
        *(float4*)(C + (size_t)grow * M + gcol) = out;
    }
}

// one wave per edge: agg[col] += dinv[row]*dinv[col] * h[row]  (256 floats)
__global__ __launch_bounds__(256) void scatter_edges_k(
    const int* __restrict__ rows, const int* __restrict__ cols,
    const float* __restrict__ dinv, const float* __restrict__ h,
    float* agg, int E)
{
    int e = blockIdx.x * 4 + (threadIdx.x >> 6);
    if (e >= E) return;
    int lane = threadIdx.x & 63;
    int r = rows[e];
    int c = cols[e];
    float w = dinv[r] * dinv[c];
    float4 v = *(const float4*)(h + (size_t)r * 256 + lane * 4);
    float* ap = agg + (size_t)c * 256 + lane * 4;
    atomicAdd(ap + 0, w * v.x);
    atomicAdd(ap + 1, w * v.y);
    atomicAdd(ap + 2, w * v.z);
    atomicAdd(ap + 3, w * v.w);
}

// out = relu(agg + dinv[node]^2 * h)   (self-loop folded in), float4-wide
__global__ __launch_bounds__(256) void finalize_relu_k(
    const float* __restrict__ agg, const float* __restrict__ h,
    const float* __restrict__ dinv, float* __restrict__ out, int nvec)
{
    int i = blockIdx.x * 256 + threadIdx.x;
    if (i >= nvec) return;
    int node = i >> 6;              // 64 float4 per 256-wide row
    float w = dinv[node];
    w = w * w;
    float4 a = ((const float4*)agg)[i];
    float4 hh = ((const float4*)h)[i];
    float4 r;
    r.x = fmaxf(fmaf(w, hh.x, a.x), 0.f);
    r.y = fmaxf(fmaf(w, hh.y, a.y), 0.f);
    r.z = fmaxf(fmaf(w, hh.z, a.z), 0.f);
    r.w = fmaxf(fmaf(w, hh.w, a.w), 0.f);
    ((float4*)out)[i] = r;
}

static inline int cdiv(int a, int b) { return (a + b - 1) / b; }

extern "C" void kernel_launch(void* const* d_in, const int* in_sizes, int n_in,
                              void* d_out, int out_size, void* d_ws, size_t ws_size,
                              hipStream_t stream) {
    const float* x  = (const float*)d_in[0];
    const int*  ei  = (const int*)d_in[1];
    const float* W1 = (const float*)d_in[2];
    const float* b1 = (const float*)d_in[3];
    const float* W2 = (const float*)d_in[4];
    const float* b2 = (const float*)d_in[5];
    const float* Wh = (const float*)d_in[6];
    const float* bh = (const float*)d_in[7];
    float* out = (float*)d_out;

    const int N = in_sizes[0] / 256;       // 50000
    const int E = in_sizes[1] / 2;         // 400000
    const int H = 256;
    const int C = 64;
    const int* rows = ei;
    const int* cols = ei + E;

    char* ws = (char*)d_ws;
    float* dinv = (float*)ws;                           // N floats
    size_t off = ((size_t)N * 4 + 255) & ~(size_t)255;
    float* bufH = (float*)(ws + off);                   // N*256 f32
    float* bufA = (float*)(ws + off + (size_t)N * H * 4);

    // ---- degree / norm ----
    init_deg_k<<<cdiv(N, 256), 256, 0, stream>>>(dinv, N);
    count_deg_k<<<cdiv(E, 256), 256, 0, stream>>>(rows, dinv, E);
    dinv_k<<<cdiv(N, 256), 256, 0, stream>>>(dinv, N);

    dim3 g1(cdiv(N, TS), H / TS);
    dim3 gh(cdiv(N, TS), C / TS);
    int nvec = N * (H / 4);

    // ---- layer 1 ----
    gemm_bias_k<<<g1, 256, 0, stream>>>(x, W1, b1, bufH, N, 256, H);
    hipMemsetAsync(bufA, 0, (size_t)N * H * 4, stream);
    scatter_edges_k<<<cdiv(E, 4), 256, 0, stream>>>(rows, cols, dinv, bufH, bufA, E);
    finalize_relu_k<<<cdiv(nvec, 256), 256, 0, stream>>>(bufA, bufH, dinv, bufA, nvec);

    // ---- layer 2 ----
    gemm_bias_k<<<g1, 256, 0, stream>>>(bufA, W2, b2, bufH, N, H, H);
    hipMemsetAsync(bufA, 0, (size_t)N * H * 4, stream);
    scatter_edges_k<<<cdiv(E, 4), 256, 0, stream>>>(rows, cols, dinv, bufH, bufA, E);
    finalize_relu_k<<<cdiv(nvec, 256), 256, 0, stream>>>(bufA, bufH, dinv, bufA, nvec);

    // ---- head ----
    gemm_bias_k<<<gh, 256, 0, stream>>>(bufA, Wh, bh, out, N, H, C);
}

// Round 2
// 467.876 us; speedup vs baseline: 6.4548x; 6.4548x over previous
//
#include <hip/hip_runtime.h>
#include <hip/hip_bf16.h>

#define TS 64
#define KC 64

static inline int cdiv(int a, int b) { return (a + b - 1) / b; }

__global__ __launch_bounds__(256) void init_deg_k(float* deg, int N) {
    int i = blockIdx.x * 256 + threadIdx.x;
    if (i < N) deg[i] = 1.0f;  // self loop contributes 1
}

__global__ __launch_bounds__(256) void count_deg_k(const int* __restrict__ rows, float* deg, int E) {
    int e = blockIdx.x * 256 + threadIdx.x;
    if (e < E) atomicAdd(&deg[rows[e]], 1.0f);
}

__global__ __launch_bounds__(256) void dinv_k(float* deg, int N) {
    int i = blockIdx.x * 256 + threadIdx.x;
    if (i < N) deg[i] = rsqrtf(deg[i]);  // deg >= 1 guaranteed
}

__global__ __launch_bounds__(256) void count_indeg_k(const int* __restrict__ cols, int* indeg, int E) {
    int e = blockIdx.x * 256 + threadIdx.x;
    if (e < E) atomicAdd(&indeg[cols[e]], 1);
}

// block scans 1024 elements (4/thread), writes per-block exclusive scan + block sum
__global__ __launch_bounds__(256) void scan_block_k(
    const int* __restrict__ indeg, int* __restrict__ rowstart,
    int* __restrict__ bsums, int N)
{
    __shared__ int smem[256];
    int b = blockIdx.x, t = threadIdx.x;
    int base = b * 1024 + t * 4;
    int v0 = (base + 0 < N) ? indeg[base + 0] : 0;
    int v1 = (base + 1 < N) ? indeg[base + 1] : 0;
    int v2 = (base + 2 < N) ? indeg[base + 2] : 0;
    int v3 = (base + 3 < N) ? indeg[base + 3] : 0;
    int s = v0 + v1 + v2 + v3;
    smem[t] = s;
    __syncthreads();
    for (int off = 1; off < 256; off <<= 1) {
        int x = smem[t];
        int y = (t >= off) ? smem[t - off] : 0;
        __syncthreads();
        smem[t] = x + y;
        __syncthreads();
    }
    int excl = smem[t] - s;
    if (base + 0 < N) rowstart[base + 0] = excl;
    if (base + 1 < N) rowstart[base + 1] = excl + v0;
    if (base + 2 < N) rowstart[base + 2] = excl + v0 + v1;
    if (base + 3 < N) rowstart[base + 3] = excl + v0 + v1 + v2;
    if (t == 255) bsums[b] = smem[255];
}

// single block: exclusive scan of block sums (nb <= 256); also writes rowstart[N]=E
__global__ __launch_bounds__(256) void scan_sums_k(int* bsums, int nb, int* rowstart, int N, int E) {
    __shared__ int smem[256];
    int t = threadIdx.x;
    int v = (t < nb) ? bsums[t] : 0;
    smem[t] = v;
    __syncthreads();
    for (int off = 1; off < 256; off <<= 1) {
        int x = smem[t];
        int y = (t >= off) ? smem[t - off] : 0;
        __syncthreads();
        smem[t] = x + y;
        __syncthreads();
    }
    if (t < nb) bsums[t] = smem[t] - v;
    if (t == 0) rowstart[N] = E;
}

// add block offsets; also init cursor = rowstart
__global__ __launch_bounds__(256) void scan_add_k(int* rowstart, int* cursor, const int* __restrict__ bsums, int N) {
    int i = blockIdx.x * 256 + threadIdx.x;
    if (i < N) {
        int v = rowstart[i] + bsums[i >> 10];
        rowstart[i] = v;
        cursor[i] = v;
    }
}

__global__ __launch_bounds__(256) void fill_csr_k(
    const int* __restrict__ rows, const int* __restrict__ cols,
    int* cursor, int* __restrict__ csr, int E)
{
    int e = blockIdx.x * 256 + threadIdx.x;
    if (e < E) {
        int pos = atomicAdd(&cursor[cols[e]], 1);
        csr[pos] = rows[e];
    }
}

// C[N,M] = (A[N,K] @ W[K,M] + bias) * (rowscale ? rowscale[row] : 1)
__global__ __launch_bounds__(256) void gemm_bias_k(
    const float* __restrict__ A, const float* __restrict__ W,
    const float* __restrict__ bias, const float* __restrict__ rowscale,
    float* __restrict__ C, int N, int K, int M)
{
    __shared__ float As[TS][KC + 4];
    __shared__ float Ws[KC][TS + 4];
    const int tid = threadIdx.x;
    const int tx = tid & 15;
    const int ty = tid >> 4;
    const int rowBase = blockIdx.x * TS;
    const int colBase = blockIdx.y * TS;

    float acc[4][4] = {};

    for (int k0 = 0; k0 < K; k0 += KC) {
        #pragma unroll
        for (int it = 0; it < 4; ++it) {
            int v = tid + 256 * it;
            int r = v >> 4;
            int kq = v & 15;
            int grow = rowBase + r;
            float4 val = make_float4(0.f, 0.f, 0.f, 0.f);
            if (grow < N) val = *(const float4*)(A + (size_t)grow * K + k0 + 4 * kq);
            *(float4*)(&As[r][4 * kq]) = val;
        }
        #pragma unroll
        for (int it = 0; it < 4; ++it) {
            int v = tid + 256 * it;
            int kk = v >> 4;
            int cq = v & 15;
            float4 val = *(const float4*)(W + (size_t)(k0 + kk) * M + colBase + 4 * cq);
            *(float4*)(&Ws[kk][4 * cq]) = val;
        }
        __syncthreads();

        #pragma unroll
        for (int k = 0; k < KC; ++k) {
            float a0 = As[ty * 4 + 0][k];
            float a1 = As[ty * 4 + 1][k];
            float a2 = As[ty * 4 + 2][k];
            float a3 = As[ty * 4 + 3][k];
            float b0 = Ws[k][tx * 4 + 0];
            float b1 = Ws[k][tx * 4 + 1];
            float b2 = Ws[k][tx * 4 + 2];
            float b3 = Ws[k][tx * 4 + 3];
            acc[0][0] += a0 * b0; acc[0][1] += a0 * b1; acc[0][2] += a0 * b2; acc[0][3] += a0 * b3;
            acc[1][0] += a1 * b0; acc[1][1] += a1 * b1; acc[1][2] += a1 * b2; acc[1][3] += a1 * b3;
            acc[2][0] += a2 * b0; acc[2][1] += a2 * b1; acc[2][2] += a2 * b2; acc[2][3] += a2 * b3;
            acc[3][0] += a3 * b0; acc[3][1] += a3 * b1; acc[3][2] += a3 * b2; acc[3][3] += a3 * b3;
        }
        __syncthreads();
    }

    const int gcol = colBase + tx * 4;
    float4 bv = *(const float4*)(bias + gcol);
    #pragma unroll
    for (int i = 0; i < 4; ++i) {
        int grow = rowBase + ty * 4 + i;
        if (grow >= N) continue;
        float sc = rowscale ? rowscale[grow] : 1.0f;
        float4 out;
        out.x = (acc[i][0] + bv.x) * sc;
        out.y = (acc[i][1] + bv.y) * sc;
        out.z = (acc[i][2] + bv.z) * sc;
        out.w = (acc[i][3] + bv.w) * sc;
        *(float4*)(C + (size_t)grow * M + gcol) = out;
    }
}

// one wave per node: out[c] = relu(dinv[c] * (h'[c] + sum_{r->c} h'[r]))
__global__ __launch_bounds__(256) void gather_agg_k(
    const int* __restrict__ rowstart, const int* __restrict__ csr,
    const float* __restrict__ dinv, const float* __restrict__ hp,
    float* __restrict__ out, int N)
{
    int c = blockIdx.x * 4 + (threadIdx.x >> 6);
    if (c >= N) return;
    int lane = threadIdx.x & 63;
    int beg = rowstart[c];
    int end = rowstart[c + 1];
    float4 acc = *((const float4*)(hp + (size_t)c * 256) + lane);  // self loop
    int e = beg;
    for (; e + 1 < end; e += 2) {
        int r0 = csr[e];
        int r1 = csr[e + 1];
        float4 v0 = *((const float4*)(hp + (size_t)r0 * 256) + lane);
        float4 v1 = *((const float4*)(hp + (size_t)r1 * 256) + lane);
        acc.x += v0.x + v1.x;
        acc.y += v0.y + v1.y;
        acc.z += v0.z + v1.z;
        acc.w += v0.w + v1.w;
    }
    if (e < end) {
        int r0 = csr[e];
        float4 v0 = *((const float4*)(hp + (size_t)r0 * 256) + lane);
        acc.x += v0.x; acc.y += v0.y; acc.z += v0.z; acc.w += v0.w;
    }
    float sc = dinv[c];
    float4 o;
    o.x = fmaxf(sc * acc.x, 0.f);
    o.y = fmaxf(sc * acc.y, 0.f);
    o.z = fmaxf(sc * acc.z, 0.f);
    o.w = fmaxf(sc * acc.w, 0.f);
    *((float4*)(out + (size_t)c * 256) + lane) = o;
}

extern "C" void kernel_launch(void* const* d_in, const int* in_sizes, int n_in,
                              void* d_out, int out_size, void* d_ws, size_t ws_size,
                              hipStream_t stream) {
    const float* x  = (const float*)d_in[0];
    const int*  ei  = (const int*)d_in[1];
    const float* W1 = (const float*)d_in[2];
    const float* b1 = (const float*)d_in[3];
    const float* W2 = (const float*)d_in[4];
    const float* b2 = (const float*)d_in[5];
    const float* Wh = (const float*)d_in[6];
    const float* bh = (const float*)d_in[7];
    float* out = (float*)d_out;

    const int N = in_sizes[0] / 256;       // 50000
    const int E = in_sizes[1] / 2;         // 400000
    const int H = 256;
    const int C = 64;
    const int* rows = ei;
    const int* cols = ei + E;

    char* ws = (char*)d_ws;
    size_t off = 0;
    auto alloc = [&](size_t bytes) {
        void* p = ws + off;
        off = (off + bytes + 255) & ~(size_t)255;
        return p;
    };
    float* dinv     = (float*)alloc((size_t)N * 4);
    int*   indeg    = (int*)alloc((size_t)N * 4);        // reused as cursor
    int*   rowstart = (int*)alloc((size_t)(N + 1) * 4);
    int*   bsums    = (int*)alloc(256 * 4);
    int*   csr      = (int*)alloc((size_t)E * 4);
    float* bufH     = (float*)alloc((size_t)N * H * 4);
    float* bufA     = (float*)alloc((size_t)N * H * 4);

    const int nb = cdiv(N, 1024);  // 49 scan blocks

    // ---- norm degrees (by source, incl self loop) ----
    init_deg_k<<<cdiv(N, 256), 256, 0, stream>>>(dinv, N);
    count_deg_k<<<cdiv(E, 256), 256, 0, stream>>>(rows, dinv, E);
    dinv_k<<<cdiv(N, 256), 256, 0, stream>>>(dinv, N);

    // ---- CSR by target ----
    hipMemsetAsync(indeg, 0, (size_t)N * 4, stream);
    count_indeg_k<<<cdiv(E, 256), 256, 0, stream>>>(cols, indeg, E);
    scan_block_k<<<nb, 256, 0, stream>>>(indeg, rowstart, bsums, N);
    scan_sums_k<<<1, 256, 0, stream>>>(bsums, nb, rowstart, N, E);
    scan_add_k<<<cdiv(N, 256), 256, 0, stream>>>(rowstart, indeg, bsums, N);
    fill_csr_k<<<cdiv(E, 256), 256, 0, stream>>>(rows, cols, indeg, csr, E);

    dim3 g1(cdiv(N, TS), H / TS);
    dim3 gh(cdiv(N, TS), C / TS);

    // ---- layer 1: h' = dinv * (x@W1+b1); agg+relu -> bufA ----
    gemm_bias_k<<<g1, 256, 0, stream>>>(x, W1, b1, dinv, bufH, N, 256, H);
    gather_agg_k<<<cdiv(N, 4), 256, 0, stream>>>(rowstart, csr, dinv, bufH, bufA, N);

    // ---- layer 2 ----
    gemm_bias_k<<<g1, 256, 0, stream>>>(bufA, W2, b2, dinv, bufH, N, H, H);
    gather_agg_k<<<cdiv(N, 4), 256, 0, stream>>>(rowstart, csr, dinv, bufH, bufA, N);

    // ---- head ----
    gemm_bias_k<<<gh, 256, 0, stream>>>(bufA, Wh, bh, nullptr, out, N, H, C);
}

// Round 3
// 252.501 us; speedup vs baseline: 11.9605x; 1.8530x over previous
//
#include <hip/hip_runtime.h>
#include <hip/hip_bf16.h>

typedef __attribute__((ext_vector_type(8))) short short8;
typedef __attribute__((ext_vector_type(4))) float f32x4;

static inline int cdiv(int a, int b) { return (a + b - 1) / b; }

__device__ inline float bf2f(unsigned short u) {
    union { unsigned int u; float f; } a; a.u = ((unsigned int)u) << 16; return a.f;
}
__device__ inline unsigned short f2bf(float f) {
    union { float f; unsigned int u; } a; a.f = f;
    unsigned int r = a.u + 0x7fff + ((a.u >> 16) & 1);
    return (unsigned short)(r >> 16);
}
__device__ inline void gload_lds16(const void* g, void* l) {
    __builtin_amdgcn_global_load_lds(
        (const __attribute__((address_space(1))) unsigned int*)g,
        (__attribute__((address_space(3))) unsigned int*)l, 16, 0, 0);
}

// ---------------- preprocessing ----------------
__global__ __launch_bounds__(256) void init_deg_k(float* deg, int N) {
    int i = blockIdx.x * 256 + threadIdx.x;
    if (i < N) deg[i] = 1.0f;
}
__global__ __launch_bounds__(256) void count_deg_k(const int* __restrict__ rows, float* deg, int E) {
    int e = blockIdx.x * 256 + threadIdx.x;
    if (e < E) atomicAdd(&deg[rows[e]], 1.0f);
}
__global__ __launch_bounds__(256) void dinv_k(float* deg, int N) {
    int i = blockIdx.x * 256 + threadIdx.x;
    if (i < N) deg[i] = rsqrtf(deg[i]);
}
__global__ __launch_bounds__(256) void count_indeg_k(const int* __restrict__ cols, int* indeg, int E) {
    int e = blockIdx.x * 256 + threadIdx.x;
    if (e < E) atomicAdd(&indeg[cols[e]], 1);
}
__global__ __launch_bounds__(256) void scan_block_k(
    const int* __restrict__ indeg, int* __restrict__ rowstart, int* __restrict__ bsums, int N)
{
    __shared__ int smem[256];
    int b = blockIdx.x, t = threadIdx.x;
    int base = b * 1024 + t * 4;
    int v0 = (base + 0 < N) ? indeg[base + 0] : 0;
    int v1 = (base + 1 < N) ? indeg[base + 1] : 0;
    int v2 = (base + 2 < N) ? indeg[base + 2] : 0;
    int v3 = (base + 3 < N) ? indeg[base + 3] : 0;
    int s = v0 + v1 + v2 + v3;
    smem[t] = s;
    __syncthreads();
    for (int off = 1; off < 256; off <<= 1) {
        int x = smem[t];
        int y = (t >= off) ? smem[t - off] : 0;
        __syncthreads();
        smem[t] = x + y;
        __syncthreads();
    }
    int excl = smem[t] - s;
    if (base + 0 < N) rowstart[base + 0] = excl;
    if (base + 1 < N) rowstart[base + 1] = excl + v0;
    if (base + 2 < N) rowstart[base + 2] = excl + v0 + v1;
    if (base + 3 < N) rowstart[base + 3] = excl + v0 + v1 + v2;
    if (t == 255) bsums[b] = smem[255];
}
__global__ __launch_bounds__(256) void scan_sums_k(int* bsums, int nb, int* rowstart, int N, int E) {
    __shared__ int smem[256];
    int t = threadIdx.x;
    int v = (t < nb) ? bsums[t] : 0;
    smem[t] = v;
    __syncthreads();
    for (int off = 1; off < 256; off <<= 1) {
        int x = smem[t];
        int y = (t >= off) ? smem[t - off] : 0;
        __syncthreads();
        smem[t] = x + y;
        __syncthreads();
    }
    if (t < nb) bsums[t] = smem[t] - v;
    if (t == 0) rowstart[N] = E;
}
__global__ __launch_bounds__(256) void scan_add_k(int* rowstart, int* cursor, const int* __restrict__ bsums, int N) {
    int i = blockIdx.x * 256 + threadIdx.x;
    if (i < N) {
        int v = rowstart[i] + bsums[i >> 10];
        rowstart[i] = v;
        cursor[i] = v;
    }
}
__global__ __launch_bounds__(256) void fill_csr_k(
    const int* __restrict__ rows, const int* __restrict__ cols,
    int* cursor, int* __restrict__ csr, int E)
{
    int e = blockIdx.x * 256 + threadIdx.x;
    if (e < E) {
        int pos = atomicAdd(&cursor[cols[e]], 1);
        csr[pos] = rows[e];
    }
}

// ---------------- dtype conversion ----------------
__global__ __launch_bounds__(256) void f2b_k(const float* __restrict__ in, unsigned short* __restrict__ out, int n4) {
    int i = blockIdx.x * 256 + threadIdx.x;
    if (i >= n4) return;
    float4 v = ((const float4*)in)[i];
    ushort4 o;
    o.x = f2bf(v.x); o.y = f2bf(v.y); o.z = f2bf(v.z); o.w = f2bf(v.w);
    ((ushort4*)out)[i] = o;
}
// Wt[m][k] = bf16(W[k][m]); W is K x M row-major
__global__ __launch_bounds__(256) void transpose_b_k(const float* __restrict__ W, unsigned short* __restrict__ Wt, int K, int M) {
    int idx = blockIdx.x * 256 + threadIdx.x;
    if (idx >= K * M) return;
    int k = idx / M, m = idx % M;
    Wt[(size_t)m * K + k] = f2bf(W[idx]);
}

// ---------------- MFMA GEMM ----------------
// C[N,Ncols] = A[N,K](bf16) @ Wt[Ncols,K]^T(bf16) + bias
// MODE 0: out bf16, epilogue * rowscale[row]; MODE 1: out fp32, plain
// BM=128 fixed, BN in {64,128}, BK=64, 4 waves (2x2), wave tile 64 x BN/2
template<int BN, int MODE>
__global__ __launch_bounds__(256) void gemm_mfma_k(
    const unsigned short* __restrict__ A, const unsigned short* __restrict__ Wt,
    const float* __restrict__ bias, const float* __restrict__ rowscale,
    void* __restrict__ Cout, int N, int K, int Ncols)
{
    constexpr int NF = BN / 32;            // n-fragments per wave
    __shared__ __align__(16) unsigned short As[128 * 64];
    __shared__ __align__(16) unsigned short Bs[BN * 64];

    const int tid = threadIdx.x;
    const int wid = tid >> 6;
    const int lane = tid & 63;
    const int wr = wid >> 1;               // wave row 0..1
    const int wc = wid & 1;                // wave col 0..1
    const int rowBase = blockIdx.x * 128;
    const int colBase = blockIdx.y * BN;

    f32x4 acc[4][NF];
    #pragma unroll
    for (int m = 0; m < 4; ++m)
        #pragma unroll
        for (int n = 0; n < NF; ++n)
            acc[m][n] = (f32x4)0.0f;

    const int sslot = (lane & 7) ^ (lane >> 3);   // pre-swizzled source slot

    for (int k0 = 0; k0 < K; k0 += 64) {
        __syncthreads();   // protect LDS (prev iter readers done)
        // stage A: 16 chunks of 1KB (8 rows x 128B each); linear LDS dest,
        // XOR-swizzled global source (m173 pattern)
        #pragma unroll
        for (int it = 0; it < 4; ++it) {
            int ch = wid * 4 + it;
            int r = ch * 8 + (lane >> 3);
            int grow = rowBase + r; if (grow >= N) grow = N - 1;
            gload_lds16(A + (size_t)grow * K + k0 + sslot * 8, (void*)&As[ch * 512]);
        }
        // stage B (Wt rows are contiguous in K)
        #pragma unroll
        for (int it = 0; it < BN / 32; ++it) {
            int ch = wid * (BN / 32) + it;
            int c = ch * 8 + (lane >> 3);
            gload_lds16(Wt + (size_t)(colBase + c) * K + k0 + sslot * 8, (void*)&Bs[ch * 512]);
        }
        __syncthreads();   // compiler drains vmcnt before barrier

        #pragma unroll
        for (int ks = 0; ks < 2; ++ks) {
            short8 af[4];
            #pragma unroll
            for (int m = 0; m < 4; ++m) {
                int R = wr * 64 + m * 16 + (lane & 15);
                int p = (ks * 4 + (lane >> 4)) ^ (R & 7);
                af[m] = *(const short8*)(&As[R * 64 + p * 8]);
            }
            #pragma unroll
            for (int n = 0; n < NF; ++n) {
                int Cc = wc * (BN / 2) + n * 16 + (lane & 15);
                int p = (ks * 4 + (lane >> 4)) ^ (Cc & 7);
                short8 bf = *(const short8*)(&Bs[Cc * 64 + p * 8]);
                #pragma unroll
                for (int m = 0; m < 4; ++m)
                    acc[m][n] = __builtin_amdgcn_mfma_f32_16x16x32_bf16(af[m], bf, acc[m][n], 0, 0, 0);
            }
        }
    }

    // epilogue: C/D layout col=lane&15, row=(lane>>4)*4+q  [m89-verified]
    float bv[NF];
    int colv[NF];
    #pragma unroll
    for (int n = 0; n < NF; ++n) {
        colv[n] = colBase + wc * (BN / 2) + n * 16 + (lane & 15);
        bv[n] = bias[colv[n]];
    }
    #pragma unroll
    for (int m = 0; m < 4; ++m) {
        #pragma unroll
        for (int q = 0; q < 4; ++q) {
            int row = rowBase + wr * 64 + m * 16 + (lane >> 4) * 4 + q;
            if (row >= N) continue;
            if (MODE == 0) {
                float sc = rowscale[row];
                unsigned short* Cb = (unsigned short*)Cout;
                #pragma unroll
                for (int n = 0; n < NF; ++n)
                    Cb[(size_t)row * Ncols + colv[n]] = f2bf((acc[m][n][q] + bv[n]) * sc);
            } else {
                float* Cf = (float*)Cout;
                #pragma unroll
                for (int n = 0; n < NF; ++n)
                    Cf[(size_t)row * Ncols + colv[n]] = acc[m][n][q] + bv[n];
            }
        }
    }
}

// ---------------- gather aggregate (bf16 in/out, fp32 accum) ----------------
__global__ __launch_bounds__(256) void gather_agg_k(
    const int* __restrict__ rowstart, const int* __restrict__ csr,
    const float* __restrict__ dinv, const unsigned short* __restrict__ hp,
    unsigned short* __restrict__ out, int N)
{
    int c = blockIdx.x * 4 + (threadIdx.x >> 6);
    if (c >= N) return;
    int lane = threadIdx.x & 63;
    int beg = rowstart[c];
    int end = rowstart[c + 1];
    ushort4 sv = ((const ushort4*)(hp + (size_t)c * 256))[lane];  // self loop
    float a0 = bf2f(sv.x), a1 = bf2f(sv.y), a2 = bf2f(sv.z), a3 = bf2f(sv.w);
    int e = beg;
    for (; e + 1 < end; e += 2) {
        int r0 = csr[e];
        int r1 = csr[e + 1];
        ushort4 v0 = ((const ushort4*)(hp + (size_t)r0 * 256))[lane];
        ushort4 v1 = ((const ushort4*)(hp + (size_t)r1 * 256))[lane];
        a0 += bf2f(v0.x) + bf2f(v1.x);
        a1 += bf2f(v0.y) + bf2f(v1.y);
        a2 += bf2f(v0.z) + bf2f(v1.z);
        a3 += bf2f(v0.w) + bf2f(v1.w);
    }
    if (e < end) {
        int r0 = csr[e];
        ushort4 v0 = ((const ushort4*)(hp + (size_t)r0 * 256))[lane];
        a0 += bf2f(v0.x); a1 += bf2f(v0.y); a2 += bf2f(v0.z); a3 += bf2f(v0.w);
    }
    float sc = dinv[c];
    ushort4 o;
    o.x = f2bf(fmaxf(sc * a0, 0.f));
    o.y = f2bf(fmaxf(sc * a1, 0.f));
    o.z = f2bf(fmaxf(sc * a2, 0.f));
    o.w = f2bf(fmaxf(sc * a3, 0.f));
    ((ushort4*)(out + (size_t)c * 256))[lane] = o;
}

extern "C" void kernel_launch(void* const* d_in, const int* in_sizes, int n_in,
                              void* d_out, int out_size, void* d_ws, size_t ws_size,
                              hipStream_t stream) {
    const float* x  = (const float*)d_in[0];
    const int*  ei  = (const int*)d_in[1];
    const float* W1 = (const float*)d_in[2];
    const float* b1 = (const float*)d_in[3];
    const float* W2 = (const float*)d_in[4];
    const float* b2 = (const float*)d_in[5];
    const float* Wh = (const float*)d_in[6];
    const float* bh = (const float*)d_in[7];
    float* out = (float*)d_out;

    const int N = in_sizes[0] / 256;       // 50000
    const int E = in_sizes[1] / 2;         // 400000
    const int H = 256;
    const int C = 64;
    const int* rows = ei;
    const int* cols = ei + E;

    char* ws = (char*)d_ws;
    size_t off = 0;
    auto alloc = [&](size_t bytes) {
        void* p = ws + off;
        off = (off + bytes + 255) & ~(size_t)255;
        return p;
    };
    float* dinv     = (float*)alloc((size_t)N * 4);
    int*   indeg    = (int*)alloc((size_t)N * 4);        // reused as cursor
    int*   rowstart = (int*)alloc((size_t)(N + 1) * 4);
    int*   bsums    = (int*)alloc(256 * 4);
    int*   csr      = (int*)alloc((size_t)E * 4);
    unsigned short* xb   = (unsigned short*)alloc((size_t)N * H * 2);
    unsigned short* bufH = (unsigned short*)alloc((size_t)N * H * 2);
    unsigned short* bufA = (unsigned short*)alloc((size_t)N * H * 2);
    unsigned short* Wt1  = (unsigned short*)alloc((size_t)H * H * 2);
    unsigned short* Wt2  = (unsigned short*)alloc((size_t)H * H * 2);
    unsigned short* Wht  = (unsigned short*)alloc((size_t)C * H * 2);

    const int nb = cdiv(N, 1024);

    // ---- degrees / norm ----
    init_deg_k<<<cdiv(N, 256), 256, 0, stream>>>(dinv, N);
    count_deg_k<<<cdiv(E, 256), 256, 0, stream>>>(rows, dinv, E);
    dinv_k<<<cdiv(N, 256), 256, 0, stream>>>(dinv, N);

    // ---- CSR by target ----
    hipMemsetAsync(indeg, 0, (size_t)N * 4, stream);
    count_indeg_k<<<cdiv(E, 256), 256, 0, stream>>>(cols, indeg, E);
    scan_block_k<<<nb, 256, 0, stream>>>(indeg, rowstart, bsums, N);
    scan_sums_k<<<1, 256, 0, stream>>>(bsums, nb, rowstart, N, E);
    scan_add_k<<<cdiv(N, 256), 256, 0, stream>>>(rowstart, indeg, bsums, N);
    fill_csr_k<<<cdiv(E, 256), 256, 0, stream>>>(rows, cols, indeg, csr, E);

    // ---- conversions ----
    f2b_k<<<cdiv(N * H / 4, 256), 256, 0, stream>>>(x, xb, N * H / 4);
    transpose_b_k<<<cdiv(H * H, 256), 256, 0, stream>>>(W1, Wt1, H, H);
    transpose_b_k<<<cdiv(H * H, 256), 256, 0, stream>>>(W2, Wt2, H, H);
    transpose_b_k<<<cdiv(H * C, 256), 256, 0, stream>>>(Wh, Wht, H, C);

    dim3 g1(cdiv(N, 128), H / 128);
    dim3 gh(cdiv(N, 128), 1);

    // ---- layer 1 ----
    gemm_mfma_k<128, 0><<<g1, 256, 0, stream>>>(xb, Wt1, b1, dinv, bufH, N, H, H);
    gather_agg_k<<<cdiv(N, 4), 256, 0, stream>>>(rowstart, csr, dinv, bufH, bufA, N);

    // ---- layer 2 ----
    gemm_mfma_k<128, 0><<<g1, 256, 0, stream>>>(bufA, Wt2, b2, dinv, bufH, N, H, H);
    gather_agg_k<<<cdiv(N, 4), 256, 0, stream>>>(rowstart, csr, dinv, bufH, bufA, N);

    // ---- head ----
    gemm_mfma_k<64, 1><<<gh, 256, 0, stream>>>(bufA, Wht, bh, nullptr, out, N, H, C);
}